// Round 4
// baseline (155.550 us; speedup 1.0000x reference)
//
#include <hip/hip_runtime.h>
#include <math.h>

// DSA sparse attention, MI355X. B=2 H=8 S=2048 D=64 VD=64 T=128.
// fp32 in/out, int32 indices. One wave per query; 4 waves/block;
// blockIdx%16 = plane=(b*H+h) so blockIdx%8 pins each K/V plane to one XCD L2.
//
// R15: defeat compiler rematerialization. R14 post-mortem: VGPR stayed 40 --
// impossible with the 8 live uint4 buffers -- because LLVM remat'd the
// loop-invariant voffs/scs (loads from const __restrict__ memory are "free"
// to re-execute) and inserted its own draining waitcnts inside the loop,
// collapsing the pipeline to ~2 in flight. Two fixes:
//  - amdgpu_waves_per_eu(4,4): pins scheduler occupancy target to 4 waves/EU
//    (128-VGPR budget) so it stops minimizing pressure toward 8 waves.
//  - opaque in-place defs: asm("" : "+v"(x)) on every voff/sc/q value makes
//    the def un-rematerializable (compiler cannot re-derive from memory;
//    must keep in a register). Zero instruction cost.
// Hand pipeline (depth-4 pairs, counted vmcnt(6), sched_barrier per rule #18)
// unchanged from R14. Numerics identical: absmax must stay 0.0078125.

#define BB 2
#define HH 8
#define SS 2048
#define DD 64
#define VDD 64
#define TT 128
#define SCALE 0.125f
#define LOG2E 1.44269504088896340736f
#define NKV (BB * HH * SS * DD)          // 2097152 elements each for k and v

typedef __fp16 h2 __attribute__((ext_vector_type(2)));   // builtin interop type
typedef float  f2 __attribute__((ext_vector_type(2)));

__device__ __forceinline__ float bf_lo(unsigned int u) {
    return __uint_as_float(u << 16);
}
// hi bf16 WITHOUT masking: low 16 junk bits are below bf16 rounding noise.
__device__ __forceinline__ float bf_hi(unsigned int u) {
    return __uint_as_float(u);
}
__device__ __forceinline__ unsigned short f2bf_rne(float f) {
    unsigned int u = __float_as_uint(f);
    u += 0x7FFFu + ((u >> 16) & 1u);     // round-to-nearest-even
    return (unsigned short)(u >> 16);
}
__device__ __forceinline__ unsigned int pk_f16(float x, float y) {
    h2 p = __builtin_amdgcn_cvt_pkrtz(x, y);
    return __builtin_bit_cast(unsigned int, p);
}
__device__ __forceinline__ float dot2(unsigned int qh, unsigned int kh, float c) {
    return __builtin_amdgcn_fdot2(__builtin_bit_cast(h2, qh),
                                  __builtin_bit_cast(h2, kh), c, false);
}

// butterfly add via DPP: x += dpp_move(x). All 64 lanes active; row/bank
// masks full, bound_ctrl=1 (no invalid lanes in these patterns).
template <int CTRL>
__device__ __forceinline__ float dpp_add(float x) {
    int t = __builtin_amdgcn_update_dpp(0, __builtin_bit_cast(int, x),
                                        CTRL, 0xF, 0xF, true);
    return x + __builtin_bit_cast(float, t);
}
#define DPP_XOR1 0xB1    // quad_perm(1,0,3,2)
#define DPP_XOR2 0x4E    // quad_perm(2,3,0,1)
#define DPP_OQUAD 0x141  // row_half_mirror: other quad (valid after ^1,^2)
#define DPP_XOR8 0x128   // row_ror:8 == lane^8 within 16-lane row

__device__ __forceinline__ float fast_exp2(float x) {
#if __has_builtin(__builtin_amdgcn_exp2f)
    return __builtin_amdgcn_exp2f(x);
#else
    return exp2f(x);
#endif
}
__device__ __forceinline__ float fast_rcp(float x) {
#if __has_builtin(__builtin_amdgcn_rcpf)
    return __builtin_amdgcn_rcpf(x);
#else
    return 1.0f / x;
#endif
}

// ---- pre-pass: fp32 k -> f16, fp32 v -> bf16, INTERLEAVED per row:
// kv row r (r = plane*SS + s) = [ K: 32 dwords | V: 32 dwords ] = 256 B.
__global__ __launch_bounds__(256) void cvt_kv(
    const float* __restrict__ k, const float* __restrict__ v,
    unsigned int* __restrict__ kv)
{
    int i = (blockIdx.x * 256 + threadIdx.x) * 4;   // 4 floats -> 2 dwords
    if (i >= NKV) return;
    float4 kf = *(const float4*)(k + i);
    float4 vf = *(const float4*)(v + i);
    unsigned int k0 = pk_f16(kf.x, kf.y);
    unsigned int k1 = pk_f16(kf.z, kf.w);
    unsigned int v0 = (unsigned int)f2bf_rne(vf.x) | ((unsigned int)f2bf_rne(vf.y) << 16);
    unsigned int v1 = (unsigned int)f2bf_rne(vf.z) | ((unsigned int)f2bf_rne(vf.w) << 16);
    int r = i >> 6;              // row index (64 fp32 per source row)
    int c = (i & 63) >> 1;       // dword slot within 32-dword half (even)
    unsigned int* row = kv + (size_t)r * 64;
    *(uint2*)(row + c)      = make_uint2(k0, k1);
    *(uint2*)(row + 32 + c) = make_uint2(v0, v1);
}

// opaque in-place def: value can no longer be rematerialized from memory.
#define OPQ_I(x) asm volatile("" : "+v"(x))
#define OPQ_F(x) asm volatile("" : "+v"(x))

// asm gather: dst <- kv[base(SGPR) + voff(VGPR) + IMM]
#define GLD(dst, vo, IMM) \
    asm volatile("global_load_dwordx4 %0, %1, %2 offset:" #IMM \
                 : "=v"(dst) : "v"(vo), "s"(kvp))

#define WAITV(N) \
    asm volatile("s_waitcnt vmcnt(" #N ")" ::: "memory"); \
    __builtin_amdgcn_sched_barrier(0)

// one pipeline stage: wait for this pair, score+accumulate
#define BODY(TC, KB, VB) \
    { \
        float st = dot2(q0, KB.x, dot2(q1, KB.y, dot2(q2, KB.z, dot2(q3, KB.w, 0.f)))); \
        st = dpp_add<DPP_XOR1>(st); \
        st = dpp_add<DPP_XOR2>(st); \
        st = dpp_add<DPP_OQUAD>(st); \
        float e = fast_exp2(st) * scs[TC]; \
        sum += e; \
        f2 ev = {e, e}; \
        f2 vx = {bf_lo(VB.x), bf_hi(VB.x)}; \
        f2 vy = {bf_lo(VB.y), bf_hi(VB.y)}; \
        f2 vz = {bf_lo(VB.z), bf_hi(VB.z)}; \
        f2 vw = {bf_lo(VB.w), bf_hi(VB.w)}; \
        a0 = __builtin_elementwise_fma(ev, vx, a0); \
        a1 = __builtin_elementwise_fma(ev, vy, a1); \
        a2 = __builtin_elementwise_fma(ev, vz, a2); \
        a3 = __builtin_elementwise_fma(ev, vw, a3); \
    }

#define ITERP(TC, KB, VB) \
    WAITV(6); \
    BODY(TC, KB, VB); \
    GLD(KB, voffs[(TC) + 4], 0); \
    GLD(VB, voffs[(TC) + 4], 128)

// ---- main: merged no-max gather loop; hand-counted vmcnt pipeline ----
__global__ __launch_bounds__(256)
__attribute__((amdgpu_waves_per_eu(4, 4)))
void dsa_sparse_attn_bf16(
    const float* __restrict__ q,
    const unsigned int* __restrict__ kv,   // interleaved rows, 64 dwords each
    const int* __restrict__ topk_idx,
    const float* __restrict__ topk_sc,
    float* __restrict__ out)
{
    const int tid  = threadIdx.x;
    const int wave = tid >> 6;
    const int lane = tid & 63;
    const int h    = lane & 7;           // dim-group: dwords h*4..h*4+3
    const int g    = lane >> 3;          // row-group: rows t = tc*8+g
    const int h16  = h << 4;             // byte offset within row segment

    const int plane = blockIdx.x & 15;
    const int s     = (blockIdx.x >> 4) * 4 + wave;
    const int b     = plane >> 3;

    const float* qp  = q  + ((size_t)plane * SS + s) * DD;
    const char*  kvp = (const char*)(kv + (size_t)plane * (SS * 64));
    const int*   ip  = topk_idx + ((size_t)b * SS + s) * TT;
    const float* scp = topk_sc  + ((size_t)b * SS + s) * TT;
    float*       op  = out + ((size_t)plane * SS + s) * VDD;

    // all idx/sc loads independent, addresses known at t=0 (8-lane broadcast).
    // OPQ makes each value's def opaque -> cannot be remat'd inside the loop.
    int voffs[16];
    #pragma unroll
    for (int tc = 0; tc < 16; ++tc) {
        voffs[tc] = (ip[tc * 8 + g] << 8) + h16;
        OPQ_I(voffs[tc]);
    }
    float scs[16];
    #pragma unroll
    for (int tc = 0; tc < 16; ++tc) {
        scs[tc] = scp[tc * 8 + g];
        OPQ_F(scs[tc]);
    }

    float4 qa = *(const float4*)(qp + h * 8);
    float4 qb = *(const float4*)(qp + h * 8 + 4);
    // scale*log2e folded into q -> scores in log2 domain; exp == exp2
    const float QS = SCALE * LOG2E;
    unsigned int q0 = pk_f16(qa.x * QS, qa.y * QS);
    unsigned int q1 = pk_f16(qa.z * QS, qa.w * QS);
    unsigned int q2 = pk_f16(qb.x * QS, qb.y * QS);
    unsigned int q3 = pk_f16(qb.z * QS, qb.w * QS);
    OPQ_I(q0); OPQ_I(q1); OPQ_I(q2); OPQ_I(q3);
    __builtin_amdgcn_sched_barrier(0);

    f2 a0 = {0.f, 0.f}, a1 = {0.f, 0.f}, a2 = {0.f, 0.f}, a3 = {0.f, 0.f};
    float sum = 0.f;

    uint4 KB0, VB0, KB1, VB1, KB2, VB2, KB3, VB3;
    // prologue: fill the 4-deep pipeline (8 loads in flight)
    GLD(KB0, voffs[0], 0); GLD(VB0, voffs[0], 128);
    GLD(KB1, voffs[1], 0); GLD(VB1, voffs[1], 128);
    GLD(KB2, voffs[2], 0); GLD(VB2, voffs[2], 128);
    GLD(KB3, voffs[3], 0); GLD(VB3, voffs[3], 128);

    ITERP( 0, KB0, VB0);
    ITERP( 1, KB1, VB1);
    ITERP( 2, KB2, VB2);
    ITERP( 3, KB3, VB3);
    ITERP( 4, KB0, VB0);
    ITERP( 5, KB1, VB1);
    ITERP( 6, KB2, VB2);
    ITERP( 7, KB3, VB3);
    ITERP( 8, KB0, VB0);
    ITERP( 9, KB1, VB1);
    ITERP(10, KB2, VB2);
    ITERP(11, KB3, VB3);
    // drain: no more issues; counted waits step down
    WAITV(6);  BODY(12, KB0, VB0);
    WAITV(4);  BODY(13, KB1, VB1);
    WAITV(2);  BODY(14, KB2, VB2);
    WAITV(0);  BODY(15, KB3, VB3);

    // cross-lane: weight-sum, then 8 output partials over row-groups (bits 3..5)
    sum = dpp_add<DPP_XOR8>(sum);
    sum += __shfl_xor(sum, 16);
    sum += __shfl_xor(sum, 32);

    float a[8] = {a0.x, a0.y, a1.x, a1.y, a2.x, a2.y, a3.x, a3.y};
    #pragma unroll
    for (int j = 0; j < 8; ++j) {
        a[j] = dpp_add<DPP_XOR8>(a[j]);
        a[j] += __shfl_xor(a[j], 16);
        a[j] += __shfl_xor(a[j], 32);
    }
    if (g == 0) {
        float inv = fast_rcp(sum + 1e-12f);
        *(float4*)(op + h * 8)     = make_float4(a[0] * inv, a[1] * inv, a[2] * inv, a[3] * inv);
        *(float4*)(op + h * 8 + 4) = make_float4(a[4] * inv, a[5] * inv, a[6] * inv, a[7] * inv);
    }
}

// ---- fallback fp32 kernel (used if ws too small) ----
__global__ __launch_bounds__(256, 4) void dsa_sparse_attn_f32(
    const float* __restrict__ q,
    const float* __restrict__ k,
    const float* __restrict__ v,
    const int* __restrict__ topk_idx,
    const float* __restrict__ topk_sc,
    float* __restrict__ out)
{
    const int tid  = threadIdx.x;
    const int wave = tid >> 6;
    const int lane = tid & 63;
    const int plane = blockIdx.x & 15;
    const int s     = (blockIdx.x >> 4) * 4 + wave;
    const int b     = plane >> 3;

    const float* qp  = q + ((size_t)plane * SS + s) * DD;
    const float* kp  = k + (size_t)plane * SS * DD;
    const float* vp  = v + (size_t)plane * SS * VDD;
    const int*   ip  = topk_idx + ((size_t)b * SS + s) * TT;
    const float* scp = topk_sc  + ((size_t)b * SS + s) * TT;
    float*       op  = out + ((size_t)plane * SS + s) * VDD;

    __shared__ int   s_idx[4][TT];
    __shared__ float s_w[4][TT];

    float sc0 = scp[lane];
    float sc1 = scp[64 + lane];
    s_idx[wave][lane]      = ip[lane];
    s_idx[wave][64 + lane] = ip[64 + lane];

    const int l = lane & 3;
    const int g = lane >> 2;
    float4 qf[4];
    #pragma unroll
    for (int j = 0; j < 4; ++j) qf[j] = *(const float4*)(qp + l * 4 + 16 * j);
    __syncthreads();

    #pragma unroll
    for (int tc = 0; tc < 8; ++tc) {
        int t = tc * 16 + g;
        const float* krow = kp + (size_t)s_idx[wave][t] * DD;
        float acc = 0.f;
        #pragma unroll
        for (int j = 0; j < 4; ++j) {
            float4 kf = *(const float4*)(krow + l * 4 + 16 * j);
            acc += qf[j].x * kf.x + qf[j].y * kf.y + qf[j].z * kf.z + qf[j].w * kf.w;
        }
        acc += __shfl_xor(acc, 1);
        acc += __shfl_xor(acc, 2);
        if (l == 0) s_w[wave][t] = acc * SCALE;
    }
    __syncthreads();

    float a0 = s_w[wave][lane];
    float a1 = s_w[wave][64 + lane];
    float m = fmaxf(a0, a1);
    #pragma unroll
    for (int off = 32; off >= 1; off >>= 1) m = fmaxf(m, __shfl_xor(m, off));
    float e0 = __expf(a0 - m) * sc0;
    float e1 = __expf(a1 - m) * sc1;
    float sum = e0 + e1;
    #pragma unroll
    for (int off = 32; off >= 1; off >>= 1) sum += __shfl_xor(sum, off);
    float inv = 1.0f / (sum + 1e-12f);
    s_w[wave][lane]      = e0 * inv;
    s_w[wave][64 + lane] = e1 * inv;
    __syncthreads();

    float acc = 0.f;
    #pragma unroll 8
    for (int t = 0; t < TT; ++t)
        acc = fmaf(s_w[wave][t], vp[(size_t)s_idx[wave][t] * VDD + lane], acc);
    op[lane] = acc;
}

extern "C" void kernel_launch(void* const* d_in, const int* in_sizes, int n_in,
                              void* d_out, int out_size, void* d_ws, size_t ws_size,
                              hipStream_t stream) {
    const float* q   = (const float*)d_in[0];
    const float* k   = (const float*)d_in[1];
    const float* v   = (const float*)d_in[2];
    const int*   idx = (const int*)d_in[3];
    const float* sc  = (const float*)d_in[4];
    float*       out = (float*)d_out;

    const size_t need = (size_t)NKV * 2 * 2;   // interleaved kv, 8.4 MB
    if (ws_size >= need) {
        unsigned int* kv = (unsigned int*)d_ws;
        hipLaunchKernelGGL(cvt_kv, dim3(NKV / 4 / 256), dim3(256), 0, stream,
                           k, v, kv);
        hipLaunchKernelGGL(dsa_sparse_attn_bf16, dim3(8192), dim3(256), 0, stream,
                           q, kv, idx, sc, out);
    } else {
        hipLaunchKernelGGL(dsa_sparse_attn_f32, dim3(8192), dim3(256), 0, stream,
                           q, k, v, idx, sc, out);
    }
}

// Round 6
// 117.990 us; speedup vs baseline: 1.3183x; 1.3183x over previous
//
#include <hip/hip_runtime.h>
#include <math.h>

// DSA sparse attention, MI355X. B=2 H=8 S=2048 D=64 VD=64 T=128.
// fp32 in/out, int32 indices. 4 waves/block; TWO queries per wave;
// blockIdx%16 = plane=(b*H+h) so blockIdx%8 pins each K/V plane to one XCD L2.
//
// R17: dual-query waves. R13/R14/R15 (register pipeline) were dismantled by
// the allocator (sink/remat/spill back to ~40 VGPR); R16 (LDS-laundered asm
// pipeline) crashed. Reverting to proven R12 structure (50.9us) and raising
// memory-level parallelism the allocator-proof way: each wave processes TWO
// independent queries (s0=..+wave*2, s1=s0+1). The two gather chains are
// independent in program order -> even conservative scheduling keeps >=2
// loads in flight (typ. 3-4 with fine-grained vmcnt), at only ~+25 VGPR
// (~65 total, inside the 64-VGPR occupancy budget -> no spill/remat).
// Grid halves to 4096 blocks; per-query numerics identical to R12
// (absmax must stay 0.0078125).

#define BB 2
#define HH 8
#define SS 2048
#define DD 64
#define VDD 64
#define TT 128
#define SCALE 0.125f
#define LOG2E 1.44269504088896340736f
#define NKV (BB * HH * SS * DD)          // 2097152 elements each for k and v

typedef __fp16 h2 __attribute__((ext_vector_type(2)));   // builtin interop type
typedef float  f2 __attribute__((ext_vector_type(2)));

__device__ __forceinline__ float bf_lo(unsigned int u) {
    return __uint_as_float(u << 16);
}
// hi bf16 WITHOUT masking: low 16 junk bits are below bf16 rounding noise.
__device__ __forceinline__ float bf_hi(unsigned int u) {
    return __uint_as_float(u);
}
__device__ __forceinline__ unsigned short f2bf_rne(float f) {
    unsigned int u = __float_as_uint(f);
    u += 0x7FFFu + ((u >> 16) & 1u);     // round-to-nearest-even
    return (unsigned short)(u >> 16);
}
__device__ __forceinline__ unsigned int pk_f16(float x, float y) {
    h2 p = __builtin_amdgcn_cvt_pkrtz(x, y);
    return __builtin_bit_cast(unsigned int, p);
}
__device__ __forceinline__ float dot2(unsigned int qh, unsigned int kh, float c) {
    return __builtin_amdgcn_fdot2(__builtin_bit_cast(h2, qh),
                                  __builtin_bit_cast(h2, kh), c, false);
}

// butterfly add via DPP: x += dpp_move(x). All 64 lanes active; row/bank
// masks full, bound_ctrl=1 (no invalid lanes in these patterns).
template <int CTRL>
__device__ __forceinline__ float dpp_add(float x) {
    int t = __builtin_amdgcn_update_dpp(0, __builtin_bit_cast(int, x),
                                        CTRL, 0xF, 0xF, true);
    return x + __builtin_bit_cast(float, t);
}
#define DPP_XOR1 0xB1    // quad_perm(1,0,3,2)
#define DPP_XOR2 0x4E    // quad_perm(2,3,0,1)
#define DPP_OQUAD 0x141  // row_half_mirror: other quad (valid after ^1,^2)
#define DPP_XOR8 0x128   // row_ror:8 == lane^8 within 16-lane row

__device__ __forceinline__ float fast_exp2(float x) {
#if __has_builtin(__builtin_amdgcn_exp2f)
    return __builtin_amdgcn_exp2f(x);
#else
    return exp2f(x);
#endif
}
__device__ __forceinline__ float fast_rcp(float x) {
#if __has_builtin(__builtin_amdgcn_rcpf)
    return __builtin_amdgcn_rcpf(x);
#else
    return 1.0f / x;
#endif
}

// ---- pre-pass: fp32 k -> f16, fp32 v -> bf16, INTERLEAVED per row:
// kv row r (r = plane*SS + s) = [ K: 32 dwords | V: 32 dwords ] = 256 B.
__global__ __launch_bounds__(256) void cvt_kv(
    const float* __restrict__ k, const float* __restrict__ v,
    unsigned int* __restrict__ kv)
{
    int i = (blockIdx.x * 256 + threadIdx.x) * 4;   // 4 floats -> 2 dwords
    if (i >= NKV) return;
    float4 kf = *(const float4*)(k + i);
    float4 vf = *(const float4*)(v + i);
    unsigned int k0 = pk_f16(kf.x, kf.y);
    unsigned int k1 = pk_f16(kf.z, kf.w);
    unsigned int v0 = (unsigned int)f2bf_rne(vf.x) | ((unsigned int)f2bf_rne(vf.y) << 16);
    unsigned int v1 = (unsigned int)f2bf_rne(vf.z) | ((unsigned int)f2bf_rne(vf.w) << 16);
    int r = i >> 6;              // row index (64 fp32 per source row)
    int c = (i & 63) >> 1;       // dword slot within 32-dword half (even)
    unsigned int* row = kv + (size_t)r * 64;
    *(uint2*)(row + c)      = make_uint2(k0, k1);
    *(uint2*)(row + 32 + c) = make_uint2(v0, v1);
}

// ---- main: dual-query merged no-max gather loop, barrier-free, LDS-free ----
__global__ __launch_bounds__(256, 4) void dsa_sparse_attn_bf16(
    const float* __restrict__ q,
    const unsigned int* __restrict__ kv,   // interleaved rows, 64 dwords each
    const int* __restrict__ topk_idx,
    const float* __restrict__ topk_sc,
    float* __restrict__ out)
{
    const int tid  = threadIdx.x;
    const int wave = tid >> 6;
    const int lane = tid & 63;
    const int h    = lane & 7;           // dim-group: dwords h*4..h*4+3
    const int g    = lane >> 3;          // row-group: rows t = tc*8+g
    const int g4   = g << 2;             // bpermute byte selector base
    const int h16  = h << 4;             // byte offset within row segment

    const int plane = blockIdx.x & 15;
    const int s0    = (blockIdx.x >> 4) * 8 + wave * 2;   // query A
    const int s1    = s0 + 1;                             // query B
    const int b     = plane >> 3;

    const char* kvp = (const char*)(kv + (size_t)plane * (SS * 64));

    const float* qpA  = q + ((size_t)plane * SS + s0) * DD;
    const float* qpB  = q + ((size_t)plane * SS + s1) * DD;
    const int*   ipA  = topk_idx + ((size_t)b * SS + s0) * TT;
    const int*   ipB  = topk_idx + ((size_t)b * SS + s1) * TT;
    const float* scpA = topk_sc  + ((size_t)b * SS + s0) * TT;
    const float* scpB = topk_sc  + ((size_t)b * SS + s1) * TT;
    float*       opA  = out + ((size_t)plane * SS + s0) * VDD;
    float*       opB  = out + ((size_t)plane * SS + s1) * VDD;

    // coalesced staging loads (both queries)
    int   iv0A = ipA[lane];
    int   iv1A = ipA[64 + lane];
    int   iv0B = ipB[lane];
    int   iv1B = ipB[64 + lane];
    float sv0A = scpA[lane];
    float sv1A = scpA[64 + lane];
    float sv0B = scpB[lane];
    float sv1B = scpB[64 + lane];

    float4 qaA = *(const float4*)(qpA + h * 8);
    float4 qbA = *(const float4*)(qpA + h * 8 + 4);
    float4 qaB = *(const float4*)(qpB + h * 8);
    float4 qbB = *(const float4*)(qpB + h * 8 + 4);
    // scale*log2e folded into q -> scores in log2 domain; exp == exp2
    const float QS = SCALE * LOG2E;
    unsigned int q0A = pk_f16(qaA.x * QS, qaA.y * QS);
    unsigned int q1A = pk_f16(qaA.z * QS, qaA.w * QS);
    unsigned int q2A = pk_f16(qbA.x * QS, qbA.y * QS);
    unsigned int q3A = pk_f16(qbA.z * QS, qbA.w * QS);
    unsigned int q0B = pk_f16(qaB.x * QS, qaB.y * QS);
    unsigned int q1B = pk_f16(qaB.z * QS, qaB.w * QS);
    unsigned int q2B = pk_f16(qbB.x * QS, qbB.y * QS);
    unsigned int q3B = pk_f16(qbB.z * QS, qbB.w * QS);

    // ---- merged loop: no max subtraction (shift cancels; |st| <~ 10) ----
    // Two independent chains (A,B) interleaved -> >=2 gathers in flight.
    f2 a0A = {0.f, 0.f}, a1A = {0.f, 0.f}, a2A = {0.f, 0.f}, a3A = {0.f, 0.f};
    f2 a0B = {0.f, 0.f}, a1B = {0.f, 0.f}, a2B = {0.f, 0.f}, a3B = {0.f, 0.f};
    float sumA = 0.f, sumB = 0.f;
    #pragma unroll
    for (int tc = 0; tc < 16; ++tc) {
        const int sel = g4 + (tc & 7) * 32;        // lane (tc&7)*8+g, in bytes
        int idxA, idxB;
        float scA, scB;
        if (tc < 8) {
            idxA = __builtin_amdgcn_ds_bpermute(sel, iv0A);
            idxB = __builtin_amdgcn_ds_bpermute(sel, iv0B);
            scA  = __builtin_bit_cast(float,
                   __builtin_amdgcn_ds_bpermute(sel, __builtin_bit_cast(int, sv0A)));
            scB  = __builtin_bit_cast(float,
                   __builtin_amdgcn_ds_bpermute(sel, __builtin_bit_cast(int, sv0B)));
        } else {
            idxA = __builtin_amdgcn_ds_bpermute(sel, iv1A);
            idxB = __builtin_amdgcn_ds_bpermute(sel, iv1B);
            scA  = __builtin_bit_cast(float,
                   __builtin_amdgcn_ds_bpermute(sel, __builtin_bit_cast(int, sv1A)));
            scB  = __builtin_bit_cast(float,
                   __builtin_amdgcn_ds_bpermute(sel, __builtin_bit_cast(int, sv1B)));
        }
        const unsigned int offA = ((unsigned int)idxA << 8) + h16;  // row*256+h*16
        const unsigned int offB = ((unsigned int)idxB << 8) + h16;
        uint4 kkA = *(const uint4*)(kvp + offA);          // K segment A
        uint4 kkB = *(const uint4*)(kvp + offB);          // K segment B
        uint4 vvA = *(const uint4*)(kvp + offA + 128);    // V segment A
        uint4 vvB = *(const uint4*)(kvp + offB + 128);    // V segment B

        float stA = dot2(q0A, kkA.x, dot2(q1A, kkA.y, dot2(q2A, kkA.z, dot2(q3A, kkA.w, 0.f))));
        float stB = dot2(q0B, kkB.x, dot2(q1B, kkB.y, dot2(q2B, kkB.z, dot2(q3B, kkB.w, 0.f))));
        stA = dpp_add<DPP_XOR1>(stA);
        stB = dpp_add<DPP_XOR1>(stB);
        stA = dpp_add<DPP_XOR2>(stA);
        stB = dpp_add<DPP_XOR2>(stB);
        stA = dpp_add<DPP_OQUAD>(stA);
        stB = dpp_add<DPP_OQUAD>(stB);
        float eA = fast_exp2(stA) * scA;
        float eB = fast_exp2(stB) * scB;
        sumA += eA;
        sumB += eB;
        f2 evA = {eA, eA};
        f2 evB = {eB, eB};
        f2 vxA = {bf_lo(vvA.x), bf_hi(vvA.x)};
        f2 vyA = {bf_lo(vvA.y), bf_hi(vvA.y)};
        f2 vzA = {bf_lo(vvA.z), bf_hi(vvA.z)};
        f2 vwA = {bf_lo(vvA.w), bf_hi(vvA.w)};
        a0A = __builtin_elementwise_fma(evA, vxA, a0A);
        a1A = __builtin_elementwise_fma(evA, vyA, a1A);
        a2A = __builtin_elementwise_fma(evA, vzA, a2A);
        a3A = __builtin_elementwise_fma(evA, vwA, a3A);
        f2 vxB = {bf_lo(vvB.x), bf_hi(vvB.x)};
        f2 vyB = {bf_lo(vvB.y), bf_hi(vvB.y)};
        f2 vzB = {bf_lo(vvB.z), bf_hi(vvB.z)};
        f2 vwB = {bf_lo(vvB.w), bf_hi(vvB.w)};
        a0B = __builtin_elementwise_fma(evB, vxB, a0B);
        a1B = __builtin_elementwise_fma(evB, vyB, a1B);
        a2B = __builtin_elementwise_fma(evB, vzB, a2B);
        a3B = __builtin_elementwise_fma(evB, vwB, a3B);
    }

    // cross-lane: weight-sums, then 8 output partials per query
    sumA = dpp_add<DPP_XOR8>(sumA);
    sumB = dpp_add<DPP_XOR8>(sumB);
    sumA += __shfl_xor(sumA, 16);
    sumB += __shfl_xor(sumB, 16);
    sumA += __shfl_xor(sumA, 32);
    sumB += __shfl_xor(sumB, 32);

    float aA[8] = {a0A.x, a0A.y, a1A.x, a1A.y, a2A.x, a2A.y, a3A.x, a3A.y};
    float aB[8] = {a0B.x, a0B.y, a1B.x, a1B.y, a2B.x, a2B.y, a3B.x, a3B.y};
    #pragma unroll
    for (int j = 0; j < 8; ++j) {
        aA[j] = dpp_add<DPP_XOR8>(aA[j]);
        aB[j] = dpp_add<DPP_XOR8>(aB[j]);
        aA[j] += __shfl_xor(aA[j], 16);
        aB[j] += __shfl_xor(aB[j], 16);
        aA[j] += __shfl_xor(aA[j], 32);
        aB[j] += __shfl_xor(aB[j], 32);
    }
    if (g == 0) {
        float invA = fast_rcp(sumA + 1e-12f);
        float invB = fast_rcp(sumB + 1e-12f);
        *(float4*)(opA + h * 8)     = make_float4(aA[0] * invA, aA[1] * invA, aA[2] * invA, aA[3] * invA);
        *(float4*)(opA + h * 8 + 4) = make_float4(aA[4] * invA, aA[5] * invA, aA[6] * invA, aA[7] * invA);
        *(float4*)(opB + h * 8)     = make_float4(aB[0] * invB, aB[1] * invB, aB[2] * invB, aB[3] * invB);
        *(float4*)(opB + h * 8 + 4) = make_float4(aB[4] * invB, aB[5] * invB, aB[6] * invB, aB[7] * invB);
    }
}

// ---- fallback fp32 kernel (used if ws too small) ----
__global__ __launch_bounds__(256, 4) void dsa_sparse_attn_f32(
    const float* __restrict__ q,
    const float* __restrict__ k,
    const float* __restrict__ v,
    const int* __restrict__ topk_idx,
    const float* __restrict__ topk_sc,
    float* __restrict__ out)
{
    const int tid  = threadIdx.x;
    const int wave = tid >> 6;
    const int lane = tid & 63;
    const int plane = blockIdx.x & 15;
    const int s     = (blockIdx.x >> 4) * 4 + wave;
    const int b     = plane >> 3;

    const float* qp  = q + ((size_t)plane * SS + s) * DD;
    const float* kp  = k + (size_t)plane * SS * DD;
    const float* vp  = v + (size_t)plane * SS * VDD;
    const int*   ip  = topk_idx + ((size_t)b * SS + s) * TT;
    const float* scp = topk_sc  + ((size_t)b * SS + s) * TT;
    float*       op  = out + ((size_t)plane * SS + s) * VDD;

    __shared__ int   s_idx[4][TT];
    __shared__ float s_w[4][TT];

    float sc0 = scp[lane];
    float sc1 = scp[64 + lane];
    s_idx[wave][lane]      = ip[lane];
    s_idx[wave][64 + lane] = ip[64 + lane];

    const int l = lane & 3;
    const int g = lane >> 2;
    float4 qf[4];
    #pragma unroll
    for (int j = 0; j < 4; ++j) qf[j] = *(const float4*)(qp + l * 4 + 16 * j);
    __syncthreads();

    #pragma unroll
    for (int tc = 0; tc < 8; ++tc) {
        int t = tc * 16 + g;
        const float* krow = kp + (size_t)s_idx[wave][t] * DD;
        float acc = 0.f;
        #pragma unroll
        for (int j = 0; j < 4; ++j) {
            float4 kf = *(const float4*)(krow + l * 4 + 16 * j);
            acc += qf[j].x * kf.x + qf[j].y * kf.y + qf[j].z * kf.z + qf[j].w * kf.w;
        }
        acc += __shfl_xor(acc, 1);
        acc += __shfl_xor(acc, 2);
        if (l == 0) s_w[wave][t] = acc * SCALE;
    }
    __syncthreads();

    float a0 = s_w[wave][lane];
    float a1 = s_w[wave][64 + lane];
    float m = fmaxf(a0, a1);
    #pragma unroll
    for (int off = 32; off >= 1; off >>= 1) m = fmaxf(m, __shfl_xor(m, off));
    float e0 = __expf(a0 - m) * sc0;
    float e1 = __expf(a1 - m) * sc1;
    float sum = e0 + e1;
    #pragma unroll
    for (int off = 32; off >= 1; off >>= 1) sum += __shfl_xor(sum, off);
    float inv = 1.0f / (sum + 1e-12f);
    s_w[wave][lane]      = e0 * inv;
    s_w[wave][64 + lane] = e1 * inv;
    __syncthreads();

    float acc = 0.f;
    #pragma unroll 8
    for (int t = 0; t < TT; ++t)
        acc = fmaf(s_w[wave][t], vp[(size_t)s_idx[wave][t] * VDD + lane], acc);
    op[lane] = acc;
}

extern "C" void kernel_launch(void* const* d_in, const int* in_sizes, int n_in,
                              void* d_out, int out_size, void* d_ws, size_t ws_size,
                              hipStream_t stream) {
    const float* q   = (const float*)d_in[0];
    const float* k   = (const float*)d_in[1];
    const float* v   = (const float*)d_in[2];
    const int*   idx = (const int*)d_in[3];
    const float* sc  = (const float*)d_in[4];
    float*       out = (float*)d_out;

    const size_t need = (size_t)NKV * 2 * 2;   // interleaved kv, 8.4 MB
    if (ws_size >= need) {
        unsigned int* kv = (unsigned int*)d_ws;
        hipLaunchKernelGGL(cvt_kv, dim3(NKV / 4 / 256), dim3(256), 0, stream,
                           k, v, kv);
        hipLaunchKernelGGL(dsa_sparse_attn_bf16, dim3(4096), dim3(256), 0, stream,
                           q, kv, idx, sc, out);
    } else {
        hipLaunchKernelGGL(dsa_sparse_attn_f32, dim3(8192), dim3(256), 0, stream,
                           q, k, v, idx, sc, out);
    }
}